// Round 10
// baseline (675.318 us; speedup 1.0000x reference)
//
#include <hip/hip_runtime.h>

typedef __attribute__((ext_vector_type(8)))  short bf16x8;   // 8 bf16 = 4 VGPR MFMA operand
typedef __attribute__((ext_vector_type(16))) float f32x16;   // 32x32 MFMA accumulator

#define XIM (32*256*256)
#define MAXFIX 16384

__device__ __forceinline__ short f2bf(float f){
    unsigned int u = __builtin_bit_cast(unsigned int, f);
    u += 0x7fffu + ((u >> 16) & 1u);           // RNE, no NaN inputs here
    return (short)(u >> 16);
}
__device__ __forceinline__ float bf2f(short s){
    unsigned int u = ((unsigned int)(unsigned short)s) << 16;
    return __builtin_bit_cast(float, u);
}
__device__ __forceinline__ void glds16(const short* g, short* l){
    __builtin_amdgcn_global_load_lds(
        (const __attribute__((address_space(1))) unsigned int*)g,
        (__attribute__((address_space(3))) unsigned int*)l,
        16, 0, 0);
}

// ---- prep: wt2[es(10)][tap9][cio4][cout32][8ci] bf16; biasmat[c32][k16]; gwT[ci32][e8*9]; cnt=0 ----
__global__ __launch_bounds__(256) void prep_weights(const float* __restrict__ ew,
                                                    const float* __restrict__ sw,
                                                    const float* __restrict__ ebv,
                                                    const float* __restrict__ sbv,
                                                    const float* __restrict__ gw,
                                                    short* __restrict__ wt2,
                                                    float* __restrict__ gwT,
                                                    int* __restrict__ cnt){
    int i = blockIdx.x * 256 + threadIdx.x;      // 371 blocks
    if(i == 0) *cnt = 0;
    if(i < 92160){
        int c7  = i & 7;
        int col = (i >> 3) & 31;                 // cout
        int cio = (i >> 8) & 3;                  // ci octet
        int rest = i >> 10;                      // 0..89
        int tap = rest % 9;
        int es  = rest / 9;                      // 0..9
        int ci  = cio*8 + c7;
        float v;
        if(es < 8)       v = ew[((es*32 + col)*32 + ci)*9 + tap];
        else if(es == 8) v = sw[(col*32 + ci)*9 + tap];
        else             v = 0.f;
        wt2[i] = f2bf(v);
    } else if(i < 92160 + 512){                  // biasmat: k<8 -> eb[k][c], k==8 -> sb[c], else 0
        int j = i - 92160, c = j >> 4, k = j & 15;
        float v = (k < 8) ? ebv[k*32 + c] : ((k == 8) ? sbv[c] : 0.f);
        wt2[i] = f2bf(v);
    } else if(i < 92672 + 2304){                 // gwT[ci][e*9+tap] contiguous per ci
        int j = i - 92672;
        int ci = j / 72, rest = j % 72;
        int e = rest / 9, tap = rest % 9;
        gwT[j] = gw[e*288 + ci*9 + tap];
    }
}

// ---- gate: no LDS, no barriers; 4 px/thread, halo via shfl; fp32 conv -> top2 -> route ----
__global__ __launch_bounds__(256) void gate_kernel(const float* __restrict__ x,
                                                   const float* __restrict__ gwT,
                                                   const float* __restrict__ gb,
                                                   short* __restrict__ route,
                                                   int* __restrict__ cnt,
                                                   int* __restrict__ fixlist){
    int raw = blockIdx.x;                        // 512; XCD chunk swizzle (512%8==0)
    int wg  = (raw & 7)*64 + (raw >> 3);
    int b   = wg >> 6;
    int y0  = (wg & 63) * 4;
    int t   = threadIdx.x;
    int r   = t >> 6;                            // row within block (wave-uniform)
    int lane = t & 63;
    int y   = y0 + r;
    const float* xim = x + (size_t)b * XIM;

    float g[8][4];
    #pragma unroll
    for(int e=0;e<8;++e)
        #pragma unroll
        for(int p=0;p<4;++p) g[e][p] = 0.f;

    for(int ci=0; ci<32; ++ci){
        float w6[3][6];                          // window xx = lane*4-1 .. lane*4+4
        #pragma unroll
        for(int kh=0;kh<3;++kh){
            int yy = y + kh - 1;
            float4 v = make_float4(0.f,0.f,0.f,0.f);
            if(yy >= 0 && yy < 256)
                v = *(const float4*)(xim + ((size_t)ci*256 + yy)*256 + lane*4);
            float lf = __shfl_up(v.w, 1);
            float rt = __shfl_down(v.x, 1);
            if(lane == 0)  lf = 0.f;
            if(lane == 63) rt = 0.f;
            w6[kh][0]=lf; w6[kh][1]=v.x; w6[kh][2]=v.y; w6[kh][3]=v.z; w6[kh][4]=v.w; w6[kh][5]=rt;
        }
        const float* gwp = gwT + ci*72;          // [e*9 + kh*3 + kw], contiguous scalar loads
        #pragma unroll
        for(int e=0;e<8;++e){
            #pragma unroll
            for(int kh=0;kh<3;++kh){
                #pragma unroll
                for(int kw=0;kw<3;++kw){
                    float wval = gwp[e*9 + kh*3 + kw];
                    #pragma unroll
                    for(int p=0;p<4;++p)
                        g[e][p] = fmaf(w6[kh][p+kw], wval, g[e][p]);
                }
            }
        }
    }

    #pragma unroll
    for(int p=0; p<4; ++p){
        int xx = lane*4 + p;
        float v1b=-1e30f, v2b=-1e30f, v3b=-1e30f, r1=0.f, r2=0.f; int i1=-1, i2=-1;
        #pragma unroll
        for(int e=0;e<8;e++){
            float se = 1.f/(1.f + expf(-g[e][p]));
            float be = se + gb[e];
            if(be > v1b){ v3b=v2b; v2b=v1b; r2=r1; i2=i1; v1b=be; r1=se; i1=e; }
            else if(be > v2b){ v3b=v2b; v2b=be; r2=se; i2=e; }
            else if(be > v3b){ v3b=be; }
        }
        if(v2b - v3b < 2e-5f){                   // too close in fp32 -> fp64 fixup pass
            int slot = atomicAdd(cnt, 1);
            if(slot < MAXFIX) fixlist[slot] = (b << 16) | (y << 8) | xx;
        }
        float m  = fmaxf(r1, r2);
        float e1 = expf(r1-m), e2 = expf(r2-m);
        float inv = 1.f/(e1+e2);
        float w1 = e1*inv, w2 = e2*inv;          // ROUTE_SCALE = 1
        bf16x8 ov;
        #pragma unroll
        for(int e=0;e<8;e++){
            float dv = (e==i1) ? w1 : ((e==i2) ? w2 : 0.f);
            ov[e] = f2bf(dv);
        }
        *(bf16x8*)(route + ((size_t)(b*256 + y)*256 + xx)*8) = ov;
    }
}

// ---- fixup: fp64 re-selection for flagged pixels (rare) ----
__global__ __launch_bounds__(256) void fixup_kernel(const float* __restrict__ x,
                                                    const float* __restrict__ gw,
                                                    const float* __restrict__ gb,
                                                    const int* __restrict__ cnt,
                                                    const int* __restrict__ fixlist,
                                                    short* __restrict__ route){
    int n = *cnt; if(n > MAXFIX) n = MAXFIX;
    for(int idx = blockIdx.x*256 + threadIdx.x; idx < n; idx += 16*256){
        int pix = fixlist[idx];
        int b  = pix >> 16, y = (pix >> 8) & 255, xx = pix & 255;
        const float* xim = x + (size_t)b*XIM;
        double gd[8];
        #pragma unroll
        for(int e=0;e<8;e++) gd[e] = 0.0;
        for(int ci=0; ci<32; ++ci){
            for(int kh=0; kh<3; ++kh){
                int yy = y + kh - 1;
                if(yy < 0 || yy >= 256) continue;
                const float* xr = xim + ((size_t)ci*256 + yy)*256;
                for(int kw=0; kw<3; ++kw){
                    int xc = xx + kw - 1;
                    if(xc < 0 || xc >= 256) continue;
                    double xv = (double)xr[xc];
                    #pragma unroll
                    for(int e=0;e<8;e++) gd[e] += xv * (double)gw[e*288 + ci*9 + kh*3 + kw];
                }
            }
        }
        double b1=-1e30, b2=-1e30; double rr1=0.0, rr2=0.0; int j1=-1, j2=-1;
        #pragma unroll
        for(int e=0;e<8;e++){
            double sd = 1.0/(1.0 + exp(-gd[e]));
            double bd = sd + (double)gb[e];
            if(bd > b1){ b2=b1; rr2=rr1; j2=j1; b1=bd; rr1=sd; j1=e; }
            else if(bd > b2){ b2=bd; rr2=sd; j2=e; }
        }
        float r1 = (float)rr1, r2 = (float)rr2;
        float m  = fmaxf(r1, r2);
        float e1 = expf(r1-m), e2 = expf(r2-m);
        float inv = 1.f/(e1+e2);
        float w1 = e1*inv, w2 = e2*inv;
        bf16x8 ov;
        #pragma unroll
        for(int e=0;e<8;e++){
            float dv = (e==j1) ? w1 : ((e==j2) ? w2 : 0.f);
            ov[e] = f2bf(dv);
        }
        *(bf16x8*)(route + (size_t)pix*8) = ov;
    }
}

// ---- main: K(ci-half) split across wave pairs; 2 rows/wave; A:MFMA = 0.5; cross-hf LDS reduce ----
// 4 waves = (rp, hf). MFMA 32x32x16: A=weights(M=cout), B=x(N=px). glds dbuf per expert.
__global__ __launch_bounds__(256, 3) void moe_main(const float* __restrict__ x,
                                                   const short* __restrict__ wt2,
                                                   const short* __restrict__ route,
                                                   float* __restrict__ out){
    __shared__ __align__(16) short xt[6*4*34*8];     // [row6][cio4][px34][8ci] bf16, 13.06 KB
    __shared__ __align__(16) short wlds[2*9216];     // dbuf: [tap9][cio4][cout32][8ci], 2x18 KB
    int raw = blockIdx.x;                            // 4096; XCD chunk swizzle (4096%8==0)
    int wg  = (raw & 7)*512 + (raw >> 3);
    int b   = wg >> 9;
    int rem = wg & 511;
    int y0  = (rem >> 3) * 4;
    int x0  = (rem & 7) * 32;
    int t   = threadIdx.x;
    int wv  = t >> 6, l = t & 63, col = l & 31, hi = l >> 5;
    int rp  = wv & 1, hf = wv >> 1;                  // row-pair, ci-half

    // issue async stage of expert 0 -> buf0 (overlaps x staging)
    #pragma unroll
    for(int j=0;j<5;++j){
        int chunk = wv + 4*j;                        // wave-uniform predicate
        if(chunk < 18) glds16(wt2 + chunk*512 + l*8, wlds + chunk*512);
    }

    const float* xim = x + (size_t)b*XIM;
    {   // stage x tile rows y0-1..y0+4 (with halo) -> bf16 LDS
        int px = t & 31;
        #pragma unroll 4
        for(int i=0;i<24;i++){
            int pair = i*8 + (t>>5);                 // row*32+ci, 192 pairs
            int row = pair >> 5, ci = pair & 31;
            int yy = y0 - 1 + row, xx = x0 - 1 + px;
            float v = (yy>=0 && yy<256 && xx>=0 && xx<256) ? xim[((size_t)ci*256+yy)*256+xx] : 0.f;
            xt[((row*4 + (ci>>3))*34 + px)*8 + (ci&7)] = f2bf(v);
        }
    }
    #pragma unroll
    for(int k=0;k<2;k++){                            // halo cols px=32,33 (384 entries)
        int p = t + k*256;
        if(p < 384){
            int pair = p >> 1, px = 32 + (p & 1);
            int row = pair >> 5, ci = pair & 31;
            int yy = y0 - 1 + row, xx = x0 - 1 + px;
            float v = (yy>=0 && yy<256 && xx>=0 && xx<256) ? xim[((size_t)ci*256+yy)*256+xx] : 0.f;
            xt[((row*4 + (ci>>3))*34 + px)*8 + (ci&7)] = f2bf(v);
        }
    }
    bf16x8 biasA = *(const bf16x8*)(wt2 + 92160 + col*16 + hi*8);   // biasmat[c][k] frag

    asm volatile("s_waitcnt vmcnt(0)" ::: "memory");
    __syncthreads();                                 // xt + expert0 staged

    // B fragments for this wave's ci-half, read ONCE: 12 ds_read_b128
    // output rows 2rp,2rp+1 need xt rows 2rp .. 2rp+3
    bf16x8 Bf[4][3];                                 // [row-off][kw]
    #pragma unroll
    for(int j=0;j<4;++j)
        #pragma unroll
        for(int kw=0;kw<3;++kw)
            Bf[j][kw] = *(const bf16x8*)(&xt[(((2*rp + j)*4 + hf*2 + hi)*34 + col + kw)*8]);

    bf16x8 rfrag[2];
    #pragma unroll
    for(int ct=0;ct<2;++ct)
        rfrag[ct] = *(const bf16x8*)(route + ((size_t)(b*256 + y0 + 2*rp + ct)*256 + x0 + col)*8);

    f32x16 oa[2];
    if(hf == 0){                                     // bias via MFMA, only on hf=0 (added once)
        bf16x8 ones = {};
        ones[0] = (short)0x3F80;                     // bf16 1.0 (k=8 row selects sb)
        #pragma unroll
        for(int ct=0;ct<2;++ct){
            f32x16 z = {};
            oa[ct] = __builtin_amdgcn_mfma_f32_32x32x16_bf16(biasA, hi ? ones : rfrag[ct], z, 0,0,0);
        }
    } else {
        f32x16 z = {};
        oa[0] = z; oa[1] = z;
    }

    #pragma unroll
    for(int e=0; e<9; ++e){                          // experts 0..7, then shared (8)
        const int cur = e & 1;
        if(e < 8){                                   // prefetch next expert -> other buffer
            const short* src = wt2 + (e+1)*9216;
            short* dst = wlds + (cur^1)*9216;
            #pragma unroll
            for(int j=0;j<5;++j){
                int chunk = wv + 4*j;
                if(chunk < 18) glds16(src + chunk*512 + l*8, dst + chunk*512);
            }
        }
        const short* wb = wlds + cur*9216;
        f32x16 acc[2] = {};
        #pragma unroll
        for(int tap=0; tap<9; ++tap){                // this wave's ci-half only (K split by hf)
            const int kh = tap/3, kw = tap - kh*3;
            bf16x8 a = *(const bf16x8*)(&wb[((tap*4 + hf*2 + hi)*32 + col)*8]);
            acc[0] = __builtin_amdgcn_mfma_f32_32x32x16_bf16(a, Bf[kh  ][kw], acc[0], 0,0,0);
            acc[1] = __builtin_amdgcn_mfma_f32_32x32x16_bf16(a, Bf[kh+1][kw], acc[1], 0,0,0);
        }
        #pragma unroll
        for(int ct=0;ct<2;++ct){
            float d = (e < 8) ? bf2f(rfrag[ct][e]) : 1.0f;
            #pragma unroll
            for(int r=0;r<16;r++) oa[ct][r] += d*acc[ct][r];
        }
        if(e < 8) __syncthreads();                   // next buf staged; cur reads done before overwrite
    }

    // cross-hf reduction via buf1 (dead since e=7; e=8 uses buf0 only). 16 KB.
    float* red = (float*)(wlds + 9216);
    if(hf == 1){
        #pragma unroll
        for(int ct=0;ct<2;++ct){
            float* dst = red + ((rp*2 + ct)*64 + l)*16;
            #pragma unroll
            for(int r=0;r<16;r++) dst[r] = oa[ct][r];
        }
    }
    __syncthreads();
    if(hf == 0){
        float* ob = out + (size_t)b*XIM;
        #pragma unroll
        for(int ct=0;ct<2;++ct){
            const float* srcv = red + ((rp*2 + ct)*64 + l)*16;
            int yy = y0 + 2*rp + ct;
            #pragma unroll
            for(int r=0;r<16;r++){
                float v = oa[ct][r] + srcv[r];
                int c = hi*4 + (r&3) + 8*(r>>2);     // C/D: col=lane&31, row=(r&3)+8*(r>>2)+4*hi
                ob[((size_t)c*256 + yy)*256 + x0 + col] = v;
            }
        }
    }
}

extern "C" void kernel_launch(void* const* d_in, const int* in_sizes, int n_in,
                              void* d_out, int out_size, void* d_ws, size_t ws_size,
                              hipStream_t stream){
    (void)in_sizes; (void)n_in; (void)out_size; (void)ws_size;
    const float* x   = (const float*)d_in[0];
    const float* gw  = (const float*)d_in[1];
    const float* gb  = (const float*)d_in[2];
    const float* ew  = (const float*)d_in[3];
    const float* ebv = (const float*)d_in[4];
    const float* sw  = (const float*)d_in[5];
    const float* sbv = (const float*)d_in[6];
    float* out = (float*)d_out;

    short* route = (short*)d_ws;                          // 524288 px * 8 bf16 = 8.39 MB
    short* wt2   = route + (size_t)8*256*256*8;           // 92160 + 512 bf16
    int*   cnt   = (int*)(wt2 + 92672);
    int*   fixlist = cnt + 1;                             // MAXFIX ints
    float* gwT   = (float*)(fixlist + MAXFIX);            // 2304 f32

    prep_weights<<<dim3(371),  dim3(256), 0, stream>>>(ew, sw, ebv, sbv, gw, wt2, gwT, cnt);
    gate_kernel <<<dim3(512),  dim3(256), 0, stream>>>(x, gwT, gb, route, cnt, fixlist);
    fixup_kernel<<<dim3(16),   dim3(256), 0, stream>>>(x, gw, gb, cnt, fixlist, route);
    moe_main    <<<dim3(4096), dim3(256), 0, stream>>>(x, wt2, route, out);
}

// Round 12
// 364.834 us; speedup vs baseline: 1.8510x; 1.8510x over previous
//
#include <hip/hip_runtime.h>

typedef __attribute__((ext_vector_type(8)))  short bf16x8;   // 8 bf16 = 4 VGPR MFMA operand
typedef __attribute__((ext_vector_type(16))) float f32x16;   // 32x32 MFMA accumulator

#define XIM (32*256*256)
#define MAXFIX 16384

__device__ __forceinline__ short f2bf(float f){
    unsigned int u = __builtin_bit_cast(unsigned int, f);
    u += 0x7fffu + ((u >> 16) & 1u);           // RNE, no NaN inputs here
    return (short)(u >> 16);
}
__device__ __forceinline__ float bf2f(short s){
    unsigned int u = ((unsigned int)(unsigned short)s) << 16;
    return __builtin_bit_cast(float, u);
}
__device__ __forceinline__ void glds16(const short* g, short* l){
    __builtin_amdgcn_global_load_lds(
        (const __attribute__((address_space(1))) unsigned int*)g,
        (__attribute__((address_space(3))) unsigned int*)l,
        16, 0, 0);
}

// ---- prep: folded weights W'_e = W_e + W_s -> wt2[es8][tap9][cio4][cout32][8ci] bf16 (144KB);
//      biasmat[c32][k16] (k<8: eb+sb, else 0); gwT[ci32][e8*9] f32; cnt=0 ----
__global__ __launch_bounds__(256) void prep_weights(const float* __restrict__ ew,
                                                    const float* __restrict__ sw,
                                                    const float* __restrict__ ebv,
                                                    const float* __restrict__ sbv,
                                                    const float* __restrict__ gw,
                                                    short* __restrict__ wt2,
                                                    float* __restrict__ gwT,
                                                    int* __restrict__ cnt){
    int i = blockIdx.x * 256 + threadIdx.x;      // 299 blocks * 256 = 76544 exactly
    if(i == 0) *cnt = 0;
    if(i < 73728){
        int c7  = i & 7;
        int col = (i >> 3) & 31;                 // cout
        int cio = (i >> 8) & 3;                  // ci octet
        int rest = i >> 10;                      // 0..71
        int tap = rest % 9;
        int es  = rest / 9;                      // 0..7
        int ci  = cio*8 + c7;
        float v = ew[((es*32 + col)*32 + ci)*9 + tap] + sw[(col*32 + ci)*9 + tap];
        wt2[i] = f2bf(v);
    } else if(i < 74240){                        // biasmat
        int j = i - 73728, c = j >> 4, k = j & 15;
        float v = (k < 8) ? (ebv[k*32 + c] + sbv[c]) : 0.f;
        wt2[i] = f2bf(v);
    } else {                                     // gwT[ci][e*9+tap]
        int j = i - 74240;
        int ci = j / 72, rest = j % 72;
        int e = rest / 9, tap = rest % 9;
        gwT[j] = gw[e*288 + ci*9 + tap];
    }
}

// ---- gate: 2048 blocks x 1 row, 1 px/thread, no LDS; shfl window; fp32 conv -> top2 -> route ----
__global__ __launch_bounds__(256) void gate_kernel(const float* __restrict__ x,
                                                   const float* __restrict__ gwT,
                                                   const float* __restrict__ gb,
                                                   short* __restrict__ route,
                                                   int* __restrict__ cnt,
                                                   int* __restrict__ fixlist){
    int raw = blockIdx.x;                        // 2048; XCD chunk swizzle (2048%8==0)
    int wg  = (raw & 7)*256 + (raw >> 3);
    int b   = wg >> 8;
    int y   = wg & 255;
    int t   = threadIdx.x;                       // pixel column
    int lane = t & 63;
    const float* xim = x + (size_t)b * XIM;

    float g[8];
    #pragma unroll
    for(int e=0;e<8;++e) g[e] = 0.f;

    #pragma unroll 2
    for(int ci=0; ci<32; ++ci){
        float a[3][3];
        #pragma unroll
        for(int kh=0;kh<3;++kh){
            int yy = y + kh - 1;
            float c = 0.f, lf = 0.f, rt = 0.f;
            if(yy >= 0 && yy < 256){
                const float* xr = xim + ((size_t)ci*256 + yy)*256;
                c  = xr[t];                      // coalesced
                lf = __shfl_up(c, 1);
                rt = __shfl_down(c, 1);
                if(lane == 0)  lf = (t > 0)   ? xr[t-1] : 0.f;
                if(lane == 63) rt = (t < 255) ? xr[t+1] : 0.f;
            }
            a[kh][0]=lf; a[kh][1]=c; a[kh][2]=rt;
        }
        const float* gwp = gwT + ci*72;          // uniform -> s_loads
        #pragma unroll
        for(int e=0;e<8;++e)
            #pragma unroll
            for(int kh=0;kh<3;++kh)
                #pragma unroll
                for(int kw=0;kw<3;++kw)
                    g[e] = fmaf(a[kh][kw], gwp[e*9 + kh*3 + kw], g[e]);
    }

    {
        float v1b=-1e30f, v2b=-1e30f, v3b=-1e30f, r1=0.f, r2=0.f; int i1=-1, i2=-1;
        #pragma unroll
        for(int e=0;e<8;e++){
            float se = 1.f/(1.f + expf(-g[e]));
            float be = se + gb[e];
            if(be > v1b){ v3b=v2b; v2b=v1b; r2=r1; i2=i1; v1b=be; r1=se; i1=e; }
            else if(be > v2b){ v3b=v2b; v2b=be; r2=se; i2=e; }
            else if(be > v3b){ v3b=be; }
        }
        if(v2b - v3b < 2e-5f){                   // too close in fp32 -> fp64 fixup pass
            int slot = atomicAdd(cnt, 1);
            if(slot < MAXFIX) fixlist[slot] = (b << 16) | (y << 8) | t;
        }
        float m  = fmaxf(r1, r2);
        float e1 = expf(r1-m), e2 = expf(r2-m);
        float inv = 1.f/(e1+e2);
        float w1 = e1*inv, w2 = e2*inv;          // ROUTE_SCALE = 1
        bf16x8 ov;
        #pragma unroll
        for(int e=0;e<8;e++){
            float dv = (e==i1) ? w1 : ((e==i2) ? w2 : 0.f);
            ov[e] = f2bf(dv);
        }
        *(bf16x8*)(route + ((size_t)(b*256 + y)*256 + t)*8) = ov;
    }
}

// ---- fixup: fp64 re-selection for flagged pixels (rare); uses ORIGINAL gw/gb ----
__global__ __launch_bounds__(256) void fixup_kernel(const float* __restrict__ x,
                                                    const float* __restrict__ gw,
                                                    const float* __restrict__ gb,
                                                    const int* __restrict__ cnt,
                                                    const int* __restrict__ fixlist,
                                                    short* __restrict__ route){
    int n = *cnt; if(n > MAXFIX) n = MAXFIX;
    for(int idx = blockIdx.x*256 + threadIdx.x; idx < n; idx += 16*256){
        int pix = fixlist[idx];
        int b  = pix >> 16, y = (pix >> 8) & 255, xx = pix & 255;
        const float* xim = x + (size_t)b*XIM;
        double gd[8];
        #pragma unroll
        for(int e=0;e<8;e++) gd[e] = 0.0;
        for(int ci=0; ci<32; ++ci){
            for(int kh=0; kh<3; ++kh){
                int yy = y + kh - 1;
                if(yy < 0 || yy >= 256) continue;
                const float* xr = xim + ((size_t)ci*256 + yy)*256;
                for(int kw=0; kw<3; ++kw){
                    int xc = xx + kw - 1;
                    if(xc < 0 || xc >= 256) continue;
                    double xv = (double)xr[xc];
                    #pragma unroll
                    for(int e=0;e<8;e++) gd[e] += xv * (double)gw[e*288 + ci*9 + kh*3 + kw];
                }
            }
        }
        double b1=-1e30, b2=-1e30; double rr1=0.0, rr2=0.0; int j1=-1, j2=-1;
        #pragma unroll
        for(int e=0;e<8;e++){
            double sd = 1.0/(1.0 + exp(-gd[e]));
            double bd = sd + (double)gb[e];
            if(bd > b1){ b2=b1; rr2=rr1; j2=j1; b1=bd; rr1=sd; j1=e; }
            else if(bd > b2){ b2=bd; rr2=sd; j2=e; }
        }
        float r1 = (float)rr1, r2 = (float)rr2;
        float m  = fmaxf(r1, r2);
        float e1 = expf(r1-m), e2 = expf(r2-m);
        float inv = 1.f/(e1+e2);
        float w1 = e1*inv, w2 = e2*inv;
        bf16x8 ov;
        #pragma unroll
        for(int e=0;e<8;e++){
            float dv = (e==j1) ? w1 : ((e==j2) ? w2 : 0.f);
            ov[e] = f2bf(dv);
        }
        *(bf16x8*)(route + (size_t)pix*8) = ov;
    }
}

// ---- main: WEIGHTS-STATIONARY. 256 blocks (1/CU); all 8 folded experts in LDS (144KB);
//      block = 4 waves x 2 rows, loops 8 col-tiles of a row-band. No glds/barriers per expert. ----
__global__ __launch_bounds__(256) void moe_main(const float* __restrict__ x,
                                                const short* __restrict__ wt2,
                                                const short* __restrict__ route,
                                                float* __restrict__ out){
    __shared__ __align__(16) short wlds[73728];      // [es8][tap9][cio4][cout32][8ci], 144 KB
    __shared__ __align__(16) short xt[10*2*34*8];    // [row10][cic2][px34][8ci], 10.88 KB
    int bk = blockIdx.x;                             // 256
    int b  = bk >> 5;
    int y0 = (bk & 31) * 8;
    int t  = threadIdx.x;
    int wv = t >> 6, l = t & 63, col = l & 31, hi = l >> 5;

    // stage ALL folded weights once: 144 chunks of 1 KB, async
    #pragma unroll
    for(int j=0;j<36;++j){
        int c = wv + 4*j;
        glds16(wt2 + c*512 + l*8, wlds + c*512);
    }
    bf16x8 biasA = *(const bf16x8*)(wt2 + 73728 + col*16 + hi*8);

    const float* xim = x + (size_t)b*XIM;
    float* ob = out + (size_t)b*XIM;

    for(int tile=0; tile<8; ++tile){
        int x0 = tile*32;
        bf16x8 Bx[4][2][3];                          // [row-off][hf][kw] — both halves in regs
        #pragma unroll
        for(int hf=0; hf<2; ++hf){
            __syncthreads();                         // xt free (also drains weight glds on 1st)
            {   // stage rows y0-1..y0+8, ci = hf*16..+16, px x0-1..x0+32
                int px = t & 31, grp = t >> 5;
                #pragma unroll 4
                for(int i=0;i<20;++i){
                    int pair = i*8 + grp;            // 160 = row*16 + cil
                    int row = pair >> 4, cil = pair & 15, ci = hf*16 + cil;
                    int yy = y0 - 1 + row, xx = x0 - 1 + px;
                    float v = (yy>=0 && yy<256 && xx>=0 && xx<256) ? xim[((size_t)ci*256+yy)*256+xx] : 0.f;
                    xt[((row*2 + (cil>>3))*34 + px)*8 + (cil&7)] = f2bf(v);
                }
                #pragma unroll
                for(int k=0;k<2;++k){                // halo px 32,33 (320 entries)
                    int p = t + k*256;
                    if(p < 320){
                        int pair = p >> 1, px2 = 32 + (p & 1);
                        int row = pair >> 4, cil = pair & 15, ci = hf*16 + cil;
                        int yy = y0 - 1 + row, xx = x0 - 1 + px2;
                        float v = (yy>=0 && yy<256 && xx>=0 && xx<256) ? xim[((size_t)ci*256+yy)*256+xx] : 0.f;
                        xt[((row*2 + (cil>>3))*34 + px2)*8 + (cil&7)] = f2bf(v);
                    }
                }
            }
            __syncthreads();
            #pragma unroll
            for(int j=0;j<4;++j)                     // wave rows 2wv..2wv+3
                #pragma unroll
                for(int kw=0;kw<3;++kw)
                    Bx[j][hf][kw] = *(const bf16x8*)(&xt[(((2*wv + j)*2 + hi)*34 + col + kw)*8]);
        }

        // pure register/LDS compute — no barriers
        bf16x8 rfrag[2];
        f32x16 oa[2];
        #pragma unroll
        for(int ct=0;ct<2;++ct){
            int yy = y0 + 2*wv + ct;
            rfrag[ct] = *(const bf16x8*)(route + ((size_t)(b*256 + yy)*256 + x0 + col)*8);
            f32x16 z = {};
            oa[ct] = __builtin_amdgcn_mfma_f32_32x32x16_bf16(biasA, rfrag[ct], z, 0,0,0);
        }
        #pragma unroll
        for(int es=0; es<8; ++es){
            f32x16 acc[2] = {};
            #pragma unroll
            for(int tap=0; tap<9; ++tap){
                const int kh = tap/3, kw = tap - kh*3;
                #pragma unroll
                for(int hf=0; hf<2; ++hf){
                    bf16x8 a = *(const bf16x8*)(&wlds[(((es*9 + tap)*4 + hf*2 + hi)*32 + col)*8]);
                    acc[0] = __builtin_amdgcn_mfma_f32_32x32x16_bf16(a, Bx[kh  ][hf][kw], acc[0], 0,0,0);
                    acc[1] = __builtin_amdgcn_mfma_f32_32x32x16_bf16(a, Bx[kh+1][hf][kw], acc[1], 0,0,0);
                }
            }
            #pragma unroll
            for(int ct=0;ct<2;++ct){
                float d = bf2f(rfrag[ct][es]);
                #pragma unroll
                for(int r=0;r<16;r++) oa[ct][r] += d*acc[ct][r];
            }
        }
        #pragma unroll
        for(int ct=0;ct<2;++ct){
            int yy = y0 + 2*wv + ct;
            #pragma unroll
            for(int r=0;r<16;r++){
                int c = hi*4 + (r&3) + 8*(r>>2);     // C/D: col=lane&31, row=(r&3)+8*(r>>2)+4*hi
                ob[((size_t)c*256 + yy)*256 + x0 + col] = oa[ct][r];
            }
        }
    }
}

extern "C" void kernel_launch(void* const* d_in, const int* in_sizes, int n_in,
                              void* d_out, int out_size, void* d_ws, size_t ws_size,
                              hipStream_t stream){
    (void)in_sizes; (void)n_in; (void)out_size; (void)ws_size;
    const float* x   = (const float*)d_in[0];
    const float* gw  = (const float*)d_in[1];
    const float* gb  = (const float*)d_in[2];
    const float* ew  = (const float*)d_in[3];
    const float* ebv = (const float*)d_in[4];
    const float* sw  = (const float*)d_in[5];
    const float* sbv = (const float*)d_in[6];
    float* out = (float*)d_out;

    short* route = (short*)d_ws;                          // 524288 px * 8 bf16 = 8.39 MB
    short* wt2   = route + (size_t)8*256*256*8;           // 74240 bf16 (weights+bias)
    int*   cnt   = (int*)(wt2 + 74240);
    int*   fixlist = cnt + 1;                             // MAXFIX ints
    float* gwT   = (float*)(fixlist + MAXFIX);            // 2304 f32

    prep_weights<<<dim3(299),  dim3(256), 0, stream>>>(ew, sw, ebv, sbv, gw, wt2, gwT, cnt);
    gate_kernel <<<dim3(2048), dim3(256), 0, stream>>>(x, gwT, gb, route, cnt, fixlist);
    fixup_kernel<<<dim3(16),   dim3(256), 0, stream>>>(x, gw, gb, cnt, fixlist, route);
    moe_main    <<<dim3(256),  dim3(256), 0, stream>>>(x, wt2, route, out);
}

// Round 13
// 319.367 us; speedup vs baseline: 2.1146x; 1.1424x over previous
//
#include <hip/hip_runtime.h>

typedef __attribute__((ext_vector_type(8)))  short bf16x8;   // 8 bf16 = 4 VGPR MFMA operand
typedef __attribute__((ext_vector_type(16))) float f32x16;   // 32x32 MFMA accumulator

#define XIM (32*256*256)
#define MAXFIX 16384

__device__ __forceinline__ short f2bf(float f){
    unsigned int u = __builtin_bit_cast(unsigned int, f);
    u += 0x7fffu + ((u >> 16) & 1u);           // RNE, no NaN inputs here
    return (short)(u >> 16);
}
__device__ __forceinline__ float bf2f(short s){
    unsigned int u = ((unsigned int)(unsigned short)s) << 16;
    return __builtin_bit_cast(float, u);
}
__device__ __forceinline__ void glds16(const short* g, short* l){
    __builtin_amdgcn_global_load_lds(
        (const __attribute__((address_space(1))) unsigned int*)g,
        (__attribute__((address_space(3))) unsigned int*)l,
        16, 0, 0);
}

// ---- prep: folded weights W'_e = W_e + W_s -> wt2[es8][tap9][cio4][cout32][8ci] bf16 (144KB);
//      biasmat[c32][k16] (k<8: eb+sb, else 0); cnt=0 ----
__global__ __launch_bounds__(256) void prep_weights(const float* __restrict__ ew,
                                                    const float* __restrict__ sw,
                                                    const float* __restrict__ ebv,
                                                    const float* __restrict__ sbv,
                                                    short* __restrict__ wt2,
                                                    int* __restrict__ cnt){
    int i = blockIdx.x * 256 + threadIdx.x;      // 290 blocks * 256 = 74240 exactly
    if(i == 0) *cnt = 0;
    if(i < 73728){
        int c7  = i & 7;
        int col = (i >> 3) & 31;                 // cout
        int cio = (i >> 8) & 3;                  // ci octet
        int rest = i >> 10;                      // 0..71
        int tap = rest % 9;
        int es  = rest / 9;                      // 0..7
        int ci  = cio*8 + c7;
        float v = ew[((es*32 + col)*32 + ci)*9 + tap] + sw[(col*32 + ci)*9 + tap];
        wt2[i] = f2bf(v);
    } else {                                     // biasmat
        int j = i - 73728, c = j >> 4, k = j & 15;
        float v = (k < 8) ? (ebv[k*32 + c] + sbv[c]) : 0.f;
        wt2[i] = f2bf(v);
    }
}

// ---- gate (r5 structure): 1024 blocks x 2 rows; LDS float4 staging; fp32 conv -> top2 -> route ----
__global__ __launch_bounds__(256) void gate_kernel(const float* __restrict__ x,
                                                   const float* __restrict__ gw,
                                                   const float* __restrict__ gb,
                                                   short* __restrict__ route,
                                                   int* __restrict__ cnt,
                                                   int* __restrict__ fixlist){
    __shared__ float xs[32][272];                // [r4*8+ci][4+xx], 16B-aligned slots, 34.8 KB
    int raw = blockIdx.x;                        // 1024; XCD chunk swizzle (1024%8==0)
    int wg  = (raw & 7)*128 + (raw >> 3);
    int b   = wg >> 7;
    int y0  = (wg & 127) * 2;
    int t   = threadIdx.x;
    int wv  = t >> 6, lane = t & 63;
    const float* xim = x + (size_t)b * XIM;

    if(t < 64){                                  // edge zeros (xx=-1 -> [3], xx=256 -> [260]); persist
        int s2 = t >> 1;
        if(t & 1) xs[s2][260] = 0.f; else xs[s2][3] = 0.f;
    }

    float g[2][8];
    #pragma unroll
    for(int pr=0;pr<2;++pr)
        #pragma unroll
        for(int e=0;e<8;++e) g[pr][e] = 0.f;

    for(int cc=0; cc<4; ++cc){                   // ci chunks of 8
        __syncthreads();                         // prev reads done (also publishes edge zeros)
        #pragma unroll
        for(int sg=0; sg<8; ++sg){               // wave stages 8 of 32 segments via float4
            int seg = wv*8 + sg;
            int r4  = seg >> 3;                  // staged rows y0-1 .. y0+2 (r4 == wv)
            int ci  = (seg & 7) + cc*8;
            int yy  = y0 - 1 + r4;
            const float* xr = xim + ((size_t)ci*256 + yy)*256;
            float4 v = make_float4(0.f,0.f,0.f,0.f);
            if(yy >= 0 && yy < 256) v = *(const float4*)(xr + lane*4);
            *(float4*)(&xs[seg][4 + lane*4]) = v;
        }
        __syncthreads();
        #pragma unroll
        for(int ci=0; ci<8; ++ci){
            float sv[4][3];
            #pragma unroll
            for(int r4=0;r4<4;++r4){
                sv[r4][0] = xs[r4*8+ci][t+3];    // xx = t-1+kw -> idx xx+4 = t+3+kw
                sv[r4][1] = xs[r4*8+ci][t+4];
                sv[r4][2] = xs[r4*8+ci][t+5];
            }
            const float* gwp = gw + (cc*8 + ci)*9;     // gw[e][ci][kh][kw], e-stride 288; s_loads
            #pragma unroll
            for(int e=0;e<8;++e){
                #pragma unroll
                for(int kh=0;kh<3;++kh){
                    #pragma unroll
                    for(int kw=0;kw<3;++kw){
                        float wval = gwp[e*288 + kh*3 + kw];
                        g[0][e] = fmaf(sv[kh][kw],   wval, g[0][e]);
                        g[1][e] = fmaf(sv[kh+1][kw], wval, g[1][e]);
                    }
                }
            }
        }
    }

    #pragma unroll
    for(int pr=0; pr<2; ++pr){
        int y = y0 + pr;
        float v1b=-1e30f, v2b=-1e30f, v3b=-1e30f, r1=0.f, r2=0.f; int i1=-1, i2=-1;
        #pragma unroll
        for(int e=0;e<8;e++){
            float se = 1.f/(1.f + expf(-g[pr][e]));
            float be = se + gb[e];
            if(be > v1b){ v3b=v2b; v2b=v1b; r2=r1; i2=i1; v1b=be; r1=se; i1=e; }
            else if(be > v2b){ v3b=v2b; v2b=be; r2=se; i2=e; }
            else if(be > v3b){ v3b=be; }
        }
        if(v2b - v3b < 2e-5f){                   // too close in fp32 -> fp64 fixup pass
            int slot = atomicAdd(cnt, 1);
            if(slot < MAXFIX) fixlist[slot] = (b << 16) | (y << 8) | t;
        }
        float m  = fmaxf(r1, r2);
        float e1 = expf(r1-m), e2 = expf(r2-m);
        float inv = 1.f/(e1+e2);
        float w1 = e1*inv, w2 = e2*inv;          // ROUTE_SCALE = 1
        bf16x8 ov;
        #pragma unroll
        for(int e=0;e<8;e++){
            float dv = (e==i1) ? w1 : ((e==i2) ? w2 : 0.f);
            ov[e] = f2bf(dv);
        }
        *(bf16x8*)(route + ((size_t)(b*256 + y)*256 + t)*8) = ov;
    }
}

// ---- fixup: fp64 re-selection for flagged pixels (rare); uses ORIGINAL gw/gb ----
__global__ __launch_bounds__(256) void fixup_kernel(const float* __restrict__ x,
                                                    const float* __restrict__ gw,
                                                    const float* __restrict__ gb,
                                                    const int* __restrict__ cnt,
                                                    const int* __restrict__ fixlist,
                                                    short* __restrict__ route){
    int n = *cnt; if(n > MAXFIX) n = MAXFIX;
    for(int idx = blockIdx.x*256 + threadIdx.x; idx < n; idx += 16*256){
        int pix = fixlist[idx];
        int b  = pix >> 16, y = (pix >> 8) & 255, xx = pix & 255;
        const float* xim = x + (size_t)b*XIM;
        double gd[8];
        #pragma unroll
        for(int e=0;e<8;e++) gd[e] = 0.0;
        for(int ci=0; ci<32; ++ci){
            for(int kh=0; kh<3; ++kh){
                int yy = y + kh - 1;
                if(yy < 0 || yy >= 256) continue;
                const float* xr = xim + ((size_t)ci*256 + yy)*256;
                for(int kw=0; kw<3; ++kw){
                    int xc = xx + kw - 1;
                    if(xc < 0 || xc >= 256) continue;
                    double xv = (double)xr[xc];
                    #pragma unroll
                    for(int e=0;e<8;e++) gd[e] += xv * (double)gw[e*288 + ci*9 + kh*3 + kw];
                }
            }
        }
        double b1=-1e30, b2=-1e30; double rr1=0.0, rr2=0.0; int j1=-1, j2=-1;
        #pragma unroll
        for(int e=0;e<8;e++){
            double sd = 1.0/(1.0 + exp(-gd[e]));
            double bd = sd + (double)gb[e];
            if(bd > b1){ b2=b1; rr2=rr1; j2=j1; b1=bd; rr1=sd; j1=e; }
            else if(bd > b2){ b2=bd; rr2=sd; j2=e; }
        }
        float r1 = (float)rr1, r2 = (float)rr2;
        float m  = fmaxf(r1, r2);
        float e1 = expf(r1-m), e2 = expf(r2-m);
        float inv = 1.f/(e1+e2);
        float w1 = e1*inv, w2 = e2*inv;
        bf16x8 ov;
        #pragma unroll
        for(int e=0;e<8;e++){
            float dv = (e==j1) ? w1 : ((e==j2) ? w2 : 0.f);
            ov[e] = f2bf(dv);
        }
        *(bf16x8*)(route + (size_t)pix*8) = ov;
    }
}

// ---- main: WEIGHTS-STATIONARY + 4-chain ILP. 256 blocks (1/CU); 144KB folded weights in LDS;
//      block = 4 waves x 2 rows, 8 col-tiles; experts processed in PAIRS (4 MFMA chains). ----
__global__ __launch_bounds__(256, 1) void moe_main(const float* __restrict__ x,
                                                   const short* __restrict__ wt2,
                                                   const short* __restrict__ route,
                                                   float* __restrict__ out){
    __shared__ __align__(16) short wlds[73728];      // [es8][tap9][cio4][cout32][8ci], 144 KB
    __shared__ __align__(16) short xt[10*2*34*8];    // [row10][cic2][px34][8ci], 10.88 KB
    int bk = blockIdx.x;                             // 256
    int b  = bk >> 5;
    int y0 = (bk & 31) * 8;
    int t  = threadIdx.x;
    int wv = t >> 6, l = t & 63, col = l & 31, hi = l >> 5;

    // stage ALL folded weights once: 144 chunks of 1 KB, async
    #pragma unroll
    for(int j=0;j<36;++j){
        int c = wv + 4*j;
        glds16(wt2 + c*512 + l*8, wlds + c*512);
    }
    bf16x8 biasA = *(const bf16x8*)(wt2 + 73728 + col*16 + hi*8);

    const float* xim = x + (size_t)b*XIM;
    float* ob = out + (size_t)b*XIM;

    for(int tile=0; tile<8; ++tile){
        int x0 = tile*32;
        bf16x8 Bx[4][2][3];                          // [row-off][hf][kw] — both halves in regs
        #pragma unroll
        for(int hf=0; hf<2; ++hf){
            __syncthreads();                         // xt free (also drains weight glds on 1st)
            {   // stage rows y0-1..y0+8, ci = hf*16..+16, px x0-1..x0+32
                int px = t & 31, grp = t >> 5;
                #pragma unroll 4
                for(int i=0;i<20;++i){
                    int pair = i*8 + grp;            // 160 = row*16 + cil
                    int row = pair >> 4, cil = pair & 15, ci = hf*16 + cil;
                    int yy = y0 - 1 + row, xx = x0 - 1 + px;
                    float v = (yy>=0 && yy<256 && xx>=0 && xx<256) ? xim[((size_t)ci*256+yy)*256+xx] : 0.f;
                    xt[((row*2 + (cil>>3))*34 + px)*8 + (cil&7)] = f2bf(v);
                }
                #pragma unroll
                for(int k=0;k<2;++k){                // halo px 32,33 (320 entries)
                    int p = t + k*256;
                    if(p < 320){
                        int pair = p >> 1, px2 = 32 + (p & 1);
                        int row = pair >> 4, cil = pair & 15, ci = hf*16 + cil;
                        int yy = y0 - 1 + row, xx = x0 - 1 + px2;
                        float v = (yy>=0 && yy<256 && xx>=0 && xx<256) ? xim[((size_t)ci*256+yy)*256+xx] : 0.f;
                        xt[((row*2 + (cil>>3))*34 + px2)*8 + (cil&7)] = f2bf(v);
                    }
                }
            }
            __syncthreads();
            #pragma unroll
            for(int j=0;j<4;++j)                     // wave rows 2wv..2wv+3
                #pragma unroll
                for(int kw=0;kw<3;++kw)
                    Bx[j][hf][kw] = *(const bf16x8*)(&xt[(((2*wv + j)*2 + hi)*34 + col + kw)*8]);
        }

        // pure register/LDS compute — no barriers
        bf16x8 rfrag[2];
        f32x16 oa[2];
        #pragma unroll
        for(int ct=0;ct<2;++ct){
            int yy = y0 + 2*wv + ct;
            rfrag[ct] = *(const bf16x8*)(route + ((size_t)(b*256 + yy)*256 + x0 + col)*8);
            f32x16 z = {};
            oa[ct] = __builtin_amdgcn_mfma_f32_32x32x16_bf16(biasA, rfrag[ct], z, 0,0,0);
        }
        #pragma unroll
        for(int ep=0; ep<4; ++ep){                   // expert PAIRS -> 4 independent MFMA chains
            const int e0 = ep*2;
            f32x16 acc[2][2] = {};                   // [es-in-pair][ct]
            #pragma unroll
            for(int tap=0; tap<9; ++tap){
                const int kh = tap/3, kw = tap - kh*3;
                #pragma unroll
                for(int hf=0; hf<2; ++hf){
                    const int ai = (((e0*9 + tap)*4 + hf*2 + hi)*32 + col)*8;
                    bf16x8 a0 = *(const bf16x8*)(&wlds[ai]);
                    bf16x8 a1 = *(const bf16x8*)(&wlds[ai + 9*1024]);   // next expert stride: 9*4*32*8
                    acc[0][0] = __builtin_amdgcn_mfma_f32_32x32x16_bf16(a0, Bx[kh  ][hf][kw], acc[0][0], 0,0,0);
                    acc[0][1] = __builtin_amdgcn_mfma_f32_32x32x16_bf16(a0, Bx[kh+1][hf][kw], acc[0][1], 0,0,0);
                    acc[1][0] = __builtin_amdgcn_mfma_f32_32x32x16_bf16(a1, Bx[kh  ][hf][kw], acc[1][0], 0,0,0);
                    acc[1][1] = __builtin_amdgcn_mfma_f32_32x32x16_bf16(a1, Bx[kh+1][hf][kw], acc[1][1], 0,0,0);
                }
            }
            #pragma unroll
            for(int ct=0;ct<2;++ct){
                float d0 = bf2f(rfrag[ct][e0]);
                float d1 = bf2f(rfrag[ct][e0+1]);
                #pragma unroll
                for(int r=0;r<16;r++) oa[ct][r] += d0*acc[0][ct][r] + d1*acc[1][ct][r];
            }
        }
        #pragma unroll
        for(int ct=0;ct<2;++ct){
            int yy = y0 + 2*wv + ct;
            #pragma unroll
            for(int r=0;r<16;r++){
                int c = hi*4 + (r&3) + 8*(r>>2);     // C/D: col=lane&31, row=(r&3)+8*(r>>2)+4*hi
                ob[((size_t)c*256 + yy)*256 + x0 + col] = oa[ct][r];
            }
        }
    }
}

extern "C" void kernel_launch(void* const* d_in, const int* in_sizes, int n_in,
                              void* d_out, int out_size, void* d_ws, size_t ws_size,
                              hipStream_t stream){
    (void)in_sizes; (void)n_in; (void)out_size; (void)ws_size;
    const float* x   = (const float*)d_in[0];
    const float* gw  = (const float*)d_in[1];
    const float* gb  = (const float*)d_in[2];
    const float* ew  = (const float*)d_in[3];
    const float* ebv = (const float*)d_in[4];
    const float* sw  = (const float*)d_in[5];
    const float* sbv = (const float*)d_in[6];
    float* out = (float*)d_out;

    short* route = (short*)d_ws;                          // 524288 px * 8 bf16 = 8.39 MB
    short* wt2   = route + (size_t)8*256*256*8;           // 74240 bf16 (weights+bias)
    int*   cnt   = (int*)(wt2 + 74240);
    int*   fixlist = cnt + 1;                             // MAXFIX ints

    prep_weights<<<dim3(290),  dim3(256), 0, stream>>>(ew, sw, ebv, sbv, wt2, cnt);
    gate_kernel <<<dim3(1024), dim3(256), 0, stream>>>(x, gw, gb, route, cnt, fixlist);
    fixup_kernel<<<dim3(16),   dim3(256), 0, stream>>>(x, gw, gb, cnt, fixlist, route);
    moe_main    <<<dim3(256),  dim3(256), 0, stream>>>(x, wt2, route, out);
}

// Round 14
// 237.636 us; speedup vs baseline: 2.8418x; 1.3439x over previous
//
#include <hip/hip_runtime.h>

typedef __attribute__((ext_vector_type(8)))  short bf16x8;   // 8 bf16 = 4 VGPR MFMA operand
typedef __attribute__((ext_vector_type(16))) float f32x16;   // 32x32 MFMA accumulator

#define XIM (32*256*256)

__device__ __forceinline__ short f2bf(float f){
    unsigned int u = __builtin_bit_cast(unsigned int, f);
    u += 0x7fffu + ((u >> 16) & 1u);           // RNE, no NaN inputs here
    return (short)(u >> 16);
}
__device__ __forceinline__ float bf2f(short s){
    unsigned int u = ((unsigned int)(unsigned short)s) << 16;
    return __builtin_bit_cast(float, u);
}
__device__ __forceinline__ void glds16(const short* g, short* l){
    __builtin_amdgcn_global_load_lds(
        (const __attribute__((address_space(1))) unsigned int*)g,
        (__attribute__((address_space(3))) unsigned int*)l,
        16, 0, 0);
}

// ---- prep: folded weights W'_e = W_e + W_s -> wt2[es8][tap9][cio4][cout32][8ci] bf16 (144KB);
//      biasmat[c32][k16] (k<8: eb+sb, else 0) ----
__global__ __launch_bounds__(256) void prep_weights(const float* __restrict__ ew,
                                                    const float* __restrict__ sw,
                                                    const float* __restrict__ ebv,
                                                    const float* __restrict__ sbv,
                                                    short* __restrict__ wt2){
    int i = blockIdx.x * 256 + threadIdx.x;      // 290 blocks * 256 = 74240 exactly
    if(i < 73728){
        int c7  = i & 7;
        int col = (i >> 3) & 31;                 // cout
        int cio = (i >> 8) & 3;                  // ci octet
        int rest = i >> 10;                      // 0..71
        int tap = rest % 9;
        int es  = rest / 9;                      // 0..7
        int ci  = cio*8 + c7;
        float v = ew[((es*32 + col)*32 + ci)*9 + tap] + sw[(col*32 + ci)*9 + tap];
        wt2[i] = f2bf(v);
    } else {                                     // biasmat
        int j = i - 73728, c = j >> 4, k = j & 15;
        float v = (k < 8) ? (ebv[k*32 + c] + sbv[c]) : 0.f;
        wt2[i] = f2bf(v);
    }
}

// ---- gate: r5-measured-best version. 1024 blocks x 2 rows; LDS float4 staging; fp32 conv ->
//      sigmoid -> top2 (fp64 recompute when rank2/rank3 margin < 2e-5) -> softmax -> route ----
__global__ __launch_bounds__(256) void gate_kernel(const float* __restrict__ x,
                                                   const float* __restrict__ gw,
                                                   const float* __restrict__ gb,
                                                   short* __restrict__ route){
    __shared__ float xs[32][272];                // [r4*8+ci][4+xx], 16B-aligned f4 slots, 34.8 KB
    int raw = blockIdx.x;                        // 1024; XCD chunk swizzle (1024%8==0)
    int wg  = (raw & 7)*128 + (raw >> 3);
    int b   = wg >> 7;
    int y0  = (wg & 127) * 2;
    int t   = threadIdx.x;
    int wv  = t >> 6, lane = t & 63;
    const float* xim = x + (size_t)b * XIM;

    if(t < 64){                                  // edge zeros (xx=-1 -> [3], xx=256 -> [260]); persist
        int s2 = t >> 1;
        if(t & 1) xs[s2][260] = 0.f; else xs[s2][3] = 0.f;
    }

    float g[2][8];
    #pragma unroll
    for(int pr=0;pr<2;++pr)
        #pragma unroll
        for(int e=0;e<8;++e) g[pr][e] = 0.f;

    for(int cc=0; cc<4; ++cc){                   // ci chunks of 8
        __syncthreads();                         // prev chunk reads done (also covers edge zeros)
        #pragma unroll
        for(int sg=0; sg<8; ++sg){               // wave stages 8 of 32 segments via float4
            int seg = wv*8 + sg;
            int r4  = seg >> 3;                  // staged rows y0-1 .. y0+2
            int ci  = (seg & 7) + cc*8;
            int yy  = y0 - 1 + r4;
            const float* xr = xim + ((size_t)ci*256 + yy)*256;
            float4 v = make_float4(0.f,0.f,0.f,0.f);
            if(yy >= 0 && yy < 256) v = *(const float4*)(xr + lane*4);
            *(float4*)(&xs[seg][4 + lane*4]) = v;
        }
        __syncthreads();
        #pragma unroll
        for(int ci=0; ci<8; ++ci){
            float sv[4][3];
            #pragma unroll
            for(int r4=0;r4<4;++r4){
                sv[r4][0] = xs[r4*8+ci][t+3];    // xx = t-1+kw -> idx xx+4 = t+3+kw
                sv[r4][1] = xs[r4*8+ci][t+4];
                sv[r4][2] = xs[r4*8+ci][t+5];
            }
            const float* gwp = gw + (cc*8 + ci)*9;     // gw[e][ci][kh][kw], e-stride 288
            #pragma unroll
            for(int e=0;e<8;++e){
                #pragma unroll
                for(int kh=0;kh<3;++kh){
                    #pragma unroll
                    for(int kw=0;kw<3;++kw){
                        float wval = gwp[e*288 + kh*3 + kw];
                        g[0][e] = fmaf(sv[kh][kw],   wval, g[0][e]);
                        g[1][e] = fmaf(sv[kh+1][kw], wval, g[1][e]);
                    }
                }
            }
        }
    }

    #pragma unroll
    for(int pr=0; pr<2; ++pr){
        float v1b=-1e30f, v2b=-1e30f, v3b=-1e30f, r1=0.f, r2=0.f; int i1=-1, i2=-1;
        #pragma unroll
        for(int e=0;e<8;e++){
            float se = 1.f/(1.f + expf(-g[pr][e]));
            float be = se + gb[e];
            if(be > v1b){ v3b=v2b; v2b=v1b; r2=r1; i2=i1; v1b=be; r1=se; i1=e; }
            else if(be > v2b){ v3b=v2b; v2b=be; r2=se; i2=e; }
            else if(be > v3b){ v3b=be; }
        }
        if(v2b - v3b < 2e-5f){                   // fp64 recompute (rare)
            int y = y0 + pr;
            double gd[8];
            #pragma unroll
            for(int e=0;e<8;e++) gd[e] = 0.0;
            for(int ci=0; ci<32; ++ci){
                for(int kh=0; kh<3; ++kh){
                    int yy = y + kh - 1;
                    if(yy < 0 || yy >= 256) continue;
                    const float* xr = xim + ((size_t)ci*256 + yy)*256;
                    for(int kw=0; kw<3; ++kw){
                        int xx = t + kw - 1;
                        if(xx < 0 || xx >= 256) continue;
                        double xv = (double)xr[xx];
                        const float* gwp = gw + ci*9 + kh*3 + kw;
                        #pragma unroll
                        for(int e=0;e<8;e++) gd[e] += xv * (double)gwp[e*288];
                    }
                }
            }
            double b1=-1e30, b2=-1e30; double rr1=0.0, rr2=0.0; int j1=-1, j2=-1;
            #pragma unroll
            for(int e=0;e<8;e++){
                double sd = 1.0/(1.0 + exp(-gd[e]));
                double bd = sd + (double)gb[e];
                if(bd > b1){ b2=b1; rr2=rr1; j2=j1; b1=bd; rr1=sd; j1=e; }
                else if(bd > b2){ b2=bd; rr2=sd; j2=e; }
            }
            i1=j1; i2=j2; r1=(float)rr1; r2=(float)rr2;
        }
        float m  = fmaxf(r1, r2);
        float e1 = expf(r1-m), e2 = expf(r2-m);
        float inv = 1.f/(e1+e2);
        float w1 = e1*inv, w2 = e2*inv;          // ROUTE_SCALE = 1
        bf16x8 ov;
        #pragma unroll
        for(int e=0;e<8;e++){
            float dv = (e==i1) ? w1 : ((e==i2) ? w2 : 0.f);
            ov[e] = f2bf(dv);
        }
        *(bf16x8*)(route + ((size_t)(b*256 + y0 + pr)*256 + t)*8) = ov;
    }
}

// ---- main: WEIGHTS-STATIONARY, 512 thr = 8 waves x 1 row (VGPR<=128 -> 2 waves/SIMD).
//      2048 blocks (1/CU resident), 8x32 tile each. 144KB folded weights + 10.9KB xt in LDS. ----
__global__ __launch_bounds__(512, 2) void moe_main(const float* __restrict__ x,
                                                   const short* __restrict__ wt2,
                                                   const short* __restrict__ route,
                                                   float* __restrict__ out){
    __shared__ __align__(16) short wlds[73728];      // [es8][tap9][cio4][cout32][8ci], 144 KB
    __shared__ __align__(16) short xt[10*2*34*8];    // [row10][cic2][px34][8ci] one hf, 10.88 KB
    int raw = blockIdx.x;                            // 2048; XCD chunk swizzle
    int wg  = (raw & 7)*256 + (raw >> 3);
    int b   = wg >> 8;
    int y0  = ((wg >> 3) & 31) * 8;
    int x0  = (wg & 7) * 32;
    int t   = threadIdx.x;                           // 0..511
    int wv  = t >> 6, l = t & 63, col = l & 31, hi = l >> 5;

    // stage ALL folded weights once: 144 chunks of 1 KB over 8 waves, async
    #pragma unroll
    for(int j=0;j<18;++j){
        int c = wv + 8*j;
        glds16(wt2 + c*512 + l*8, wlds + c*512);
    }

    const float* xim = x + (size_t)b*XIM;
    int yy = y0 + wv;                                // this wave's output row
    bf16x8 biasA = *(const bf16x8*)(wt2 + 73728 + col*16 + hi*8);      // L2-hot
    bf16x8 rfrag = *(const bf16x8*)(route + ((size_t)(b*256 + yy)*256 + x0 + col)*8);

    // x tile: stage per ci-half into xt, cache B-frags in regs (wave rows wv..wv+2)
    bf16x8 Bf[3][2][3];                              // [kh][hf][kw] = 72 VGPR
    #pragma unroll
    for(int hf=0; hf<2; ++hf){
        if(hf) __syncthreads();                      // hf0 Bf reads done before overwrite
        {   // rows y0-1..y0+8, ci = hf*16..+15, px x0-1..x0+32
            int px = t & 31, grp = t >> 5;           // 16 groups of 32 lanes
            #pragma unroll
            for(int i=0;i<10;++i){
                int pair = i*16 + grp;               // 160 = row*16 + cil
                int row = pair >> 4, cil = pair & 15, ci = hf*16 + cil;
                int ry = y0 - 1 + row, xx = x0 - 1 + px;
                float v = (ry>=0 && ry<256 && xx>=0 && xx<256) ? xim[((size_t)ci*256+ry)*256+xx] : 0.f;
                xt[((row*2 + (cil>>3))*34 + px)*8 + (cil&7)] = f2bf(v);
            }
            if(t < 320){                             // halo px 32,33
                int pair = t >> 1, px2 = 32 + (t & 1);
                int row = pair >> 4, cil = pair & 15, ci = hf*16 + cil;
                int ry = y0 - 1 + row, xx = x0 - 1 + px2;
                float v = (ry>=0 && ry<256 && xx>=0 && xx<256) ? xim[((size_t)ci*256+ry)*256+xx] : 0.f;
                xt[((row*2 + (cil>>3))*34 + px2)*8 + (cil&7)] = f2bf(v);
            }
        }
        __syncthreads();                             // xt(hf) staged; also drains weight glds
        #pragma unroll
        for(int kh=0;kh<3;++kh)
            #pragma unroll
            for(int kw=0;kw<3;++kw)
                Bf[kh][hf][kw] = *(const bf16x8*)(&xt[(((wv+kh)*2 + hi)*34 + col + kw)*8]);
    }

    f32x16 z = {};
    f32x16 oa = __builtin_amdgcn_mfma_f32_32x32x16_bf16(biasA, rfrag, z, 0,0,0);

    #pragma unroll
    for(int es=0; es<8; ++es){                       // folded experts (shared absorbed)
        f32x16 acc = {};
        #pragma unroll
        for(int tap=0; tap<9; ++tap){
            const int kh = tap/3, kw = tap - kh*3;
            #pragma unroll
            for(int hf=0; hf<2; ++hf){
                bf16x8 a = *(const bf16x8*)(&wlds[(((es*9 + tap)*4 + hf*2 + hi)*32 + col)*8]);
                acc = __builtin_amdgcn_mfma_f32_32x32x16_bf16(a, Bf[kh][hf][kw], acc, 0,0,0);
            }
        }
        float d = bf2f(rfrag[es]);
        #pragma unroll
        for(int r=0;r<16;r++) oa[r] += d*acc[r];
    }

    float* ob = out + (size_t)b*XIM;
    #pragma unroll
    for(int r=0;r<16;r++){
        int c = hi*4 + (r&3) + 8*(r>>2);             // C/D: col=lane&31, row=(r&3)+8*(r>>2)+4*hi
        ob[((size_t)c*256 + yy)*256 + x0 + col] = oa[r];
    }
}

extern "C" void kernel_launch(void* const* d_in, const int* in_sizes, int n_in,
                              void* d_out, int out_size, void* d_ws, size_t ws_size,
                              hipStream_t stream){
    (void)in_sizes; (void)n_in; (void)out_size; (void)ws_size;
    const float* x   = (const float*)d_in[0];
    const float* gw  = (const float*)d_in[1];
    const float* gb  = (const float*)d_in[2];
    const float* ew  = (const float*)d_in[3];
    const float* ebv = (const float*)d_in[4];
    const float* sw  = (const float*)d_in[5];
    const float* sbv = (const float*)d_in[6];
    float* out = (float*)d_out;

    short* route = (short*)d_ws;                          // 524288 px * 8 bf16 = 8.39 MB
    short* wt2   = route + (size_t)8*256*256*8;           // 74240 bf16 (weights+bias)

    prep_weights<<<dim3(290),  dim3(256), 0, stream>>>(ew, sw, ebv, sbv, wt2);
    gate_kernel <<<dim3(1024), dim3(256), 0, stream>>>(x, gw, gb, route);
    moe_main    <<<dim3(2048), dim3(512), 0, stream>>>(x, wt2, route, out);
}